// Round 1
// 239.534 us; speedup vs baseline: 1.0074x; 1.0074x over previous
//
#include <hip/hip_runtime.h>
#include <hip/hip_bf16.h>
#include <math.h>

#define C_DIM 1024
#define QKS  2048    // Q|K row stride in bf16 workspace

typedef __attribute__((ext_vector_type(8))) short bf16x8;   // 8 bf16 = 4 VGPRs
typedef __attribute__((ext_vector_type(4))) float f32x4;    // MFMA C/D

__device__ __forceinline__ unsigned short f2bf(float f) {
  __hip_bfloat16 h = __float2bfloat16(f);
  return *(reinterpret_cast<unsigned short*>(&h));
}
__device__ __forceinline__ float bf2f(unsigned short u) {
  return __uint_as_float(((unsigned int)u) << 16);
}
__device__ __forceinline__ f32x4 mfma16(bf16x8 a, bf16x8 b, f32x4 c) {
  return __builtin_amdgcn_mfma_f32_16x16x32_bf16(a, b, c, 0, 0, 0);
}

// Direct global->LDS DMA, 16 B per lane. LDS dest is wave-uniform base +
// lane*16 (linear); global source is per-lane.
__device__ __forceinline__ void gload_lds16(const unsigned short* g,
                                            unsigned short* l) {
  __builtin_amdgcn_global_load_lds(
      (const __attribute__((address_space(1))) void*)(g),
      (__attribute__((address_space(3))) void*)(l), 16, 0, 0);
}

// ---------------------------------------------------------------------------
// Kernel 0a: cast x (fp32) -> xb (bf16)
// ---------------------------------------------------------------------------
__global__ __launch_bounds__(256) void cast_x(
    const float* __restrict__ x, unsigned short* __restrict__ xb) {
  const int i = (blockIdx.x * 256 + threadIdx.x) << 2;
  float4 v = *(const float4*)(x + i);
  ushort4 u;
  u.x = f2bf(v.x); u.y = f2bf(v.y); u.z = f2bf(v.z); u.w = f2bf(v.w);
  *(ushort4*)(xb + i) = u;
}

// ---------------------------------------------------------------------------
// Kernel 0b: W [1024][3072] fp32 -> WT [3072][1024] bf16
// ---------------------------------------------------------------------------
__global__ __launch_bounds__(256) void transpose_w(
    const float* __restrict__ W, unsigned short* __restrict__ WT) {
  __shared__ float Ls[64][65];
  const int n0 = blockIdx.x * 64;
  const int k0 = blockIdx.y * 64;
  const int c = (threadIdx.x & 15) << 2;
  const int r = threadIdx.x >> 4;
#pragma unroll
  for (int rr = 0; rr < 64; rr += 16) {
    float4 v = *(const float4*)(W + (size_t)(k0 + r + rr) * 3072 + n0 + c);
    Ls[r + rr][c + 0] = v.x; Ls[r + rr][c + 1] = v.y;
    Ls[r + rr][c + 2] = v.z; Ls[r + rr][c + 3] = v.w;
  }
  __syncthreads();
#pragma unroll
  for (int rr = 0; rr < 64; rr += 16) {
    const int X = r + rr;
    ushort4 u;
    u.x = f2bf(Ls[c + 0][X]); u.y = f2bf(Ls[c + 1][X]);
    u.z = f2bf(Ls[c + 2][X]); u.w = f2bf(Ls[c + 3][X]);
    *(ushort4*)(WT + (size_t)(n0 + X) * C_DIM + k0 + c) = u;
  }
}

// ---------------------------------------------------------------------------
// gemm128<MODE>: C = A @ BT^T (+bias / *scale), m97-style LDS-staged GEMM.
// 128x128 tile, BK=32, 256 threads, 4 waves x (8 m-tiles x 2 n-tiles).
// Staging is direct global->LDS DMA (global_load_lds width=16): wave w stages
// rows [w*32, w*32+32) of As and Bs; lane l -> (row = l>>2, kchunk = l&3).
// A [M][lda] bf16 k-contiguous; BT [N][ldb] bf16 k-contiguous.
// MODE 0: bf16 out, + bias[col]          (x@W -> Q|K)
// MODE 1: bf16 out, + bias[row]          (Wv^T@x^T -> V^T)
// MODE 2: bf16 out, * 1/32, lower-triangle tiles only    (S = Q K^T)
// MODE 3: fp32 out, causal k-limit, split-K atomics      (O = P V)
// ---------------------------------------------------------------------------
template <int MODE>
__global__ __launch_bounds__(256) void gemm128(
    const unsigned short* __restrict__ A, const unsigned short* __restrict__ BT,
    void* __restrict__ Cv, const float* __restrict__ bias,
    int lda, int ldb, int ldc, int T) {
  __shared__ __align__(16) unsigned short As[128][32];  // 8 KB, linear
  __shared__ __align__(16) unsigned short Bs[128][32];  // 8 KB, linear

  const int tid = threadIdx.x, lane = tid & 63, w = tid >> 6;
  const int qd = lane >> 4, n16 = lane & 15;

  int m0, n0, kbeg, kend;
  bool use_atomic = false;
  if (MODE == 2) {
    if ((int)blockIdx.x > (int)blockIdx.y) return;   // upper-triangle: skip
    m0 = blockIdx.y * 128; n0 = blockIdx.x * 128; kbeg = 0; kend = C_DIM;
  } else if (MODE == 3) {
    const int nyt = T >> 7;
    const int ex  = nyt > 16 ? nyt - 16 : 0;
    const int by  = (int)blockIdx.y;
    int bi, seg;
    if (by < nyt) { bi = by; seg = 0; } else { bi = by - ex; seg = 1; }
    const int kc = (bi + 1) << 7;                    // causal key limit
    kbeg = seg ? 2048 : 0;
    kend = seg ? kc : (kc < 2048 ? kc : 2048);
    m0 = bi << 7; n0 = blockIdx.x * 128;
    use_atomic = (kc > 2048);                        // rows pre-zeroed
  } else {
    m0 = blockIdx.y * 128; n0 = blockIdx.x * 128; kbeg = 0; kend = C_DIM;
  }

  f32x4 s[8][2];
#pragma unroll
  for (int mt = 0; mt < 8; ++mt)
#pragma unroll
    for (int j = 0; j < 2; ++j) s[mt][j] = (f32x4){0.f, 0.f, 0.f, 0.f};

  // staging map: lane -> (row within 16-row chunk, k-chunk of 8 elems)
  const int srow = lane >> 2;           // 0..15
  const int skc  = (lane & 3) << 3;     // 0,8,16,24
  const unsigned short* ag0 = A  + (size_t)(m0 + (w << 5) + srow)      * lda + kbeg + skc;
  const unsigned short* ag1 = A  + (size_t)(m0 + (w << 5) + 16 + srow) * lda + kbeg + skc;
  const unsigned short* bg0 = BT + (size_t)(n0 + (w << 5) + srow)      * ldb + kbeg + skc;
  const unsigned short* bg1 = BT + (size_t)(n0 + (w << 5) + 16 + srow) * ldb + kbeg + skc;
  unsigned short* al0 = &As[(w << 5)][0];       // wave-uniform LDS bases
  unsigned short* al1 = &As[(w << 5) + 16][0];
  unsigned short* bl0 = &Bs[(w << 5)][0];
  unsigned short* bl1 = &Bs[(w << 5) + 16][0];

  const int klen = kend - kbeg;
  for (int kk = 0; kk < klen; kk += 32) {
    __syncthreads();                 // prev tile fully consumed
    gload_lds16(ag0 + kk, al0);
    gload_lds16(ag1 + kk, al1);
    gload_lds16(bg0 + kk, bl0);
    gload_lds16(bg1 + kk, bl1);
    __syncthreads();                 // compiler drains vmcnt(0) before barrier

    bf16x8 bf0 = *(const bf16x8*)&Bs[(w << 5) + n16][qd << 3];
    bf16x8 bf1 = *(const bf16x8*)&Bs[(w << 5) + 16 + n16][qd << 3];
#pragma unroll
    for (int mt = 0; mt < 8; ++mt) {
      bf16x8 af = *(const bf16x8*)&As[(mt << 4) + n16][qd << 3];
      s[mt][0] = mfma16(af, bf0, s[mt][0]);
      s[mt][1] = mfma16(af, bf1, s[mt][1]);
    }
  }

  // ---- epilogue
  if (MODE == 3) {
    float* C = (float*)Cv;
#pragma unroll
    for (int mt = 0; mt < 8; ++mt)
#pragma unroll
      for (int j = 0; j < 2; ++j) {
        const int col = n0 + (w << 5) + (j << 4) + n16;
#pragma unroll
        for (int r = 0; r < 4; ++r) {
          const int row = m0 + (mt << 4) + (qd << 2) + r;
          if (use_atomic) atomicAdd(&C[(size_t)row * ldc + col], s[mt][j][r]);
          else            C[(size_t)row * ldc + col] = s[mt][j][r];
        }
      }
  } else {
    unsigned short* C = (unsigned short*)Cv;
#pragma unroll
    for (int mt = 0; mt < 8; ++mt)
#pragma unroll
      for (int j = 0; j < 2; ++j) {
        const int col = n0 + (w << 5) + (j << 4) + n16;
        const float bc = (MODE == 0) ? bias[col] : 0.f;
#pragma unroll
        for (int r = 0; r < 4; ++r) {
          const int row = m0 + (mt << 4) + (qd << 2) + r;
          float v = s[mt][j][r];
          if (MODE == 0) v += bc;
          if (MODE == 1) v += bias[row];
          if (MODE == 2) v *= 0.03125f;
          C[(size_t)row * ldc + col] = f2bf(v);
        }
      }
  }
}

// ---------------------------------------------------------------------------
// softmax_rows: in-place row softmax on S -> P (bf16), causal+padding masked,
// normalized (P rows sum to 1). Rows < n_padd -> zeros (fixed up later).
// Each row writes keys [0, ceil128(i+1)) so PV's tile-wide K-loop reads 0s.
// ---------------------------------------------------------------------------
__global__ __launch_bounds__(256) void softmax_rows(
    unsigned short* __restrict__ P, const int* __restrict__ np_p, int T) {
  __shared__ float red[8];
  const int i = blockIdx.x;
  const int np = *np_p;
  const int klen = ((i >> 7) + 1) << 7;
  const int tid = threadIdx.x, lane = tid & 63, w = tid >> 6;
  const int j0 = tid << 4;
  unsigned short* rowp = P + (size_t)i * T;
  const bool act = j0 < klen;

  if (i < np) {
    if (act) {
      uint4 z = {0, 0, 0, 0};
      *(uint4*)(rowp + j0) = z;
      *(uint4*)(rowp + j0 + 8) = z;
    }
    return;
  }

  float v[16];
  float mx = -3.0e38f;
  if (act) {
    uint4 u0 = *(const uint4*)(rowp + j0);
    uint4 u1 = *(const uint4*)(rowp + j0 + 8);
    const unsigned int uu[8] = {u0.x, u0.y, u0.z, u0.w, u1.x, u1.y, u1.z, u1.w};
#pragma unroll
    for (int u = 0; u < 8; ++u) {
      v[2 * u]     = bf2f(uu[u] & 0xffff);
      v[2 * u + 1] = bf2f(uu[u] >> 16);
    }
#pragma unroll
    for (int u = 0; u < 16; ++u) {
      const int j = j0 + u;
      if (j > i || j < np) v[u] = -3.0e38f;
      mx = fmaxf(mx, v[u]);
    }
  }
  mx = fmaxf(mx, __shfl_xor(mx, 32));
  mx = fmaxf(mx, __shfl_xor(mx, 16));
  mx = fmaxf(mx, __shfl_xor(mx, 8));
  mx = fmaxf(mx, __shfl_xor(mx, 4));
  mx = fmaxf(mx, __shfl_xor(mx, 2));
  mx = fmaxf(mx, __shfl_xor(mx, 1));
  if (lane == 0) red[w] = mx;
  __syncthreads();
  const float M = fmaxf(fmaxf(red[0], red[1]), fmaxf(red[2], red[3]));

  float sum = 0.f;
  if (act) {
#pragma unroll
    for (int u = 0; u < 16; ++u) {
      const float p = (v[u] > -1.0e30f) ? __expf(v[u] - M) : 0.f;
      v[u] = p;
      sum += p;
    }
  }
  sum += __shfl_xor(sum, 32);
  sum += __shfl_xor(sum, 16);
  sum += __shfl_xor(sum, 8);
  sum += __shfl_xor(sum, 4);
  sum += __shfl_xor(sum, 2);
  sum += __shfl_xor(sum, 1);
  if (lane == 0) red[4 + w] = sum;
  __syncthreads();
  const float inv = 1.0f / (red[4] + red[5] + red[6] + red[7]);

  if (act) {
    unsigned int o[8];
#pragma unroll
    for (int u = 0; u < 8; ++u) {
      const unsigned int lo = f2bf(v[2 * u] * inv);
      const unsigned int hi = f2bf(v[2 * u + 1] * inv);
      o[u] = lo | (hi << 16);
    }
    uint4 s0 = {o[0], o[1], o[2], o[3]};
    uint4 s1 = {o[4], o[5], o[6], o[7]};
    *(uint4*)(rowp + j0) = s0;
    *(uint4*)(rowp + j0 + 8) = s1;
  }
}

// ---------------------------------------------------------------------------
// zero_hi: zero out rows [2048, T) of out (atomic-accumulated region)
// ---------------------------------------------------------------------------
__global__ __launch_bounds__(256) void zero_hi(float* __restrict__ out) {
  const size_t i = ((size_t)blockIdx.x * 256 + threadIdx.x) * 4 +
                   (size_t)2048 * C_DIM;
  float4 z = {0.f, 0.f, 0.f, 0.f};
  *(float4*)(out + i) = z;
}

// ---------------------------------------------------------------------------
// padfix: rows < n_padd get uniform attention over ALL T keys (mean of V)
// ---------------------------------------------------------------------------
__global__ __launch_bounds__(256) void padfix(
    const unsigned short* __restrict__ vtb, const int* __restrict__ np_p,
    float* __restrict__ out, int T) {
  const int np = *np_p;
  const int row0 = blockIdx.x * 32;
  if (row0 >= np) return;
  const int pc = min(np - row0, 32);
  const int c4 = threadIdx.x << 2;
  float a[4] = {0.f, 0.f, 0.f, 0.f};
#pragma unroll
  for (int c = 0; c < 4; ++c) {
    const unsigned short* vr = vtb + (size_t)(c4 + c) * T;
    for (int j = 0; j < T; j += 8) {
      uint4 v = *(const uint4*)(vr + j);
      a[c] += bf2f(v.x & 0xffff) + bf2f(v.x >> 16) + bf2f(v.y & 0xffff) + bf2f(v.y >> 16)
            + bf2f(v.z & 0xffff) + bf2f(v.z >> 16) + bf2f(v.w & 0xffff) + bf2f(v.w >> 16);
    }
  }
  const float inv = 1.0f / (float)T;
  float4 rv = {a[0] * inv, a[1] * inv, a[2] * inv, a[3] * inv};
  for (int r = 0; r < pc; ++r)
    *(float4*)(out + (size_t)(row0 + r) * C_DIM + c4) = rv;
}

// ---------------------------------------------------------------------------
extern "C" void kernel_launch(void* const* d_in, const int* in_sizes, int n_in,
                              void* d_out, int out_size, void* d_ws, size_t ws_size,
                              hipStream_t stream) {
  const float* x    = (const float*)d_in[0];
  const float* W    = (const float*)d_in[1];
  const float* b    = (const float*)d_in[2];
  const int* n_padd = (const int*)d_in[3];
  float* out = (float*)d_out;

  const int T = in_sizes[0] / C_DIM;
  // ws layout (overlapping lifetimes):
  //   [0,16M)  qkb [T][2048] bf16   (Q|K, persistent until PV)
  //   [16,24M) vtb [1024][T] bf16   (V^T, persistent)
  //   [24M..)  phase1: xb [T][1024] (8M) + WT [3072][1024] (6M)
  //            phase2: P  [T][T] bf16 (33.5M) overlays xb/WT (written by
  //            S-GEMM strictly after the qkv GEMMs finish reading xb/WT)
  unsigned short* qkb = (unsigned short*)d_ws;
  unsigned short* vtb = qkb + (size_t)T * QKS;
  unsigned short* xb  = vtb + (size_t)C_DIM * T;
  unsigned short* WT  = xb  + (size_t)T * C_DIM;
  unsigned short* P   = xb;

  cast_x<<<(T * C_DIM) / 1024, 256, 0, stream>>>(x, xb);
  transpose_w<<<dim3(48, 16), 256, 0, stream>>>(W, WT);

  // Q|K = xb @ WT[0:2048]^T + b[col]
  gemm128<0><<<dim3(QKS / 128, T / 128), 256, 0, stream>>>(
      xb, WT, qkb, b, C_DIM, C_DIM, QKS, T);
  // V^T = WT[2048:3072] @ xb^T + b[2048+row]
  gemm128<1><<<dim3(T / 128, C_DIM / 128), 256, 0, stream>>>(
      WT + (size_t)QKS * C_DIM, xb, vtb, b + QKS, C_DIM, C_DIM, T, T);
  // S = Q @ K^T * 1/32  (lower-triangle tiles), bf16 [T][T]
  gemm128<2><<<dim3(T / 128, T / 128), 256, 0, stream>>>(
      qkb, qkb + C_DIM, P, b, QKS, QKS, T, T);
  // P = softmax(S) row-wise (normalized, masked)
  softmax_rows<<<T, 256, 0, stream>>>(P, n_padd, T);
  // zero atomic-target rows, then O = P @ V (causal K, split-K>=2048 atomic)
  zero_hi<<<((T - 2048) * C_DIM) / 1024, 256, 0, stream>>>(out);
  {
    const int nyt = T / 128;
    const int ex = nyt > 16 ? nyt - 16 : 0;
    gemm128<3><<<dim3(C_DIM / 128, nyt + ex), 256, 0, stream>>>(
        P, vtb, out, b, T, T, C_DIM, T);
  }
  padfix<<<T / 32, 256, 0, stream>>>(vtb, n_padd, out, T);
}